// Round 17
// baseline (72.734 us; speedup 1.0000x reference)
//
#include <hip/hip_runtime.h>

// SOM BMU: argmin_m (w_sq[m] - 2*dot(x,w[m])) -> (idx/128, idx%128).
// hh (f16-hi) MFMA GEMM emits per (row, 32-col set) a packed u64:
//   [b1key:32][b2key>>14:18][b1col:14]  (float-domain best-2; sets formed by
//   lane^8 sorted-pair merge at dump; no atomics).
// Rescore: gmin = min b1key (exact hh-min), thr = gmin+MARGIN.
//   b1<=thr & b2>thr -> direct exact fp32 wave-dot of b1col (~3/row);
//   b2(trunc)<=thr -> scan set's 32 cols 4-at-a-time (rare; truncation
//   rounds down -> never misses). Coverage: c!=b1col => key(c)>=b2k.
// Margin: |hh-true| <= ~2^-11*||x||*||w|| ~ 0.3 worst; MARGIN=0.75 covers 2E.
// GEMM shape: 128-row x 512-col chunk, BK=32, 4 waves, 32KB dbuf LDS ->
// 1024 blocks = 4 blocks/CU (r16 lesson: 64KB/2-resident starved TLP).

#define B_ROWS 4096
#define M_COLS 16384
#define KF 256
#define BM 128
#define NCHUNK 32         // 512-col chunks
#define NSTEP 32          // 4 coltiles * 8 k-steps (BK=32)
#define MARGIN 0.75f

typedef _Float16 f16x8 __attribute__((ext_vector_type(8)));
typedef float f32x4 __attribute__((ext_vector_type(4)));
typedef unsigned long long u64;

#define GLOAD16(gsrc, ldst) \
  __builtin_amdgcn_global_load_lds((const __attribute__((address_space(1))) void*)(gsrc), \
                                   (__attribute__((address_space(3))) void*)(ldst), 16, 0, 0)

// tile-major: tiles of 128 rows; per (tile,ks32): [kch=4][r=128][8] halves = 8KB
__device__ __forceinline__ size_t tm_idx(int tile, int ks, int kch, int r) {
    return ((((size_t)(tile * 8 + ks)) * 4 + kch) * 128 + r) * 8;
}

__device__ __forceinline__ unsigned fkey(float s) {
    const unsigned u = __float_as_uint(s);
    return u ^ ((unsigned)((int)u >> 31) | 0x80000000u);   // monotone total order
}
__device__ __forceinline__ float unkey(unsigned k) {
    return (k & 0x80000000u) ? __uint_as_float(k & 0x7fffffffu) : __uint_as_float(~k);
}

// ---------------- kernel 1: fused split X and W -> tile-major f16 hi (+ w_sq) ----------------
__global__ __launch_bounds__(256) void som_split(const float* __restrict__ xb,
                                                 const float* __restrict__ wt,
                                                 _Float16* __restrict__ xh,
                                                 _Float16* __restrict__ wh,
                                                 float* __restrict__ wsq) {
    const int bid = blockIdx.x;
    const bool isx = bid < (B_ROWS * 32) / 256;
    const int gid = (isx ? bid : bid - (B_ROWS * 32) / 256) * 256 + threadIdx.x;
    const float* src = isx ? xb : wt;
    _Float16* dst = isx ? xh : wh;
    const int row = gid >> 5;
    const int kg = gid & 31;
    const float4 v0 = *reinterpret_cast<const float4*>(src + (size_t)row * KF + kg * 8);
    const float4 v1 = *reinterpret_cast<const float4*>(src + (size_t)row * KF + kg * 8 + 4);
    const float vv[8] = {v0.x, v0.y, v0.z, v0.w, v1.x, v1.y, v1.z, v1.w};
    f16x8 h;
    float s = 0.0f;
#pragma unroll
    for (int j = 0; j < 8; ++j) {
        h[j] = (_Float16)vv[j];
        s += vv[j] * vv[j];
    }
    *reinterpret_cast<f16x8*>(dst + tm_idx(row >> 7, kg >> 2, kg & 3, row & 127)) = h;
    if (!isx) {
#pragma unroll
        for (int off = 16; off > 0; off >>= 1) s += __shfl_down(s, off, 64);
        if (kg == 0) wsq[row] = s;   // lanes 0 and 32 each own a row
    }
}

// ---------------- kernel 2: hh GEMM (BK=32, 4 blk/CU) + per-set best-2 ----------------
__global__ __launch_bounds__(256, 4) void som_main(const _Float16* __restrict__ xh,
                                                   const _Float16* __restrict__ wh,
                                                   const float* __restrict__ wsq,
                                                   u64* __restrict__ plist) {
    __shared__ _Float16 lds[2][2][4096];   // [buf][A,B][kch=4][r=128][8], 32 KB

    const int tid = threadIdx.x;
    const int lane = tid & 63;
    const int frow = lane & 15;
    const int kch = lane >> 4;
    const int wid = tid >> 6;
    const int wr = wid >> 1;      // wave row (0..1): 64 rows
    const int wc = wid & 1;       // wave col (0..1): 64 cols

    // bijective XCD swizzle (1024 blocks, 1024%8==0)
    const int id = blockIdx.x;
    const int swz = (id & 7) * 128 + (id >> 3);
    const int bx = swz & 31;      // row tile (0..31)
    const int by = swz >> 5;      // col chunk (0..31), 512 cols each
    const int rowbase = bx * BM;

    const int ebase = (tid & 192) * 8;   // wave-uniform LDS base (halves)
    const int tid8 = tid * 8;

    float b1v[16], b2v[16];       // per-slot best-2 scores over this thread's 16 cols
    unsigned b1c[16];
#pragma unroll
    for (int i = 0; i < 16; ++i) { b1v[i] = b2v[i] = 3.4e38f; b1c[i] = 0u; }

    f32x4 acc[4][4];

#define STAGE(buf_, step_) do {                                               \
    const int ct_ = (step_) >> 3, ks_ = (step_) & 7;                          \
    const size_t ab_ = (size_t)(bx * 8 + ks_) * 4096;                         \
    const size_t bb_ = (size_t)((by * 4 + ct_) * 8 + ks_) * 4096;             \
    GLOAD16(xh + ab_ + tid8,        &lds[buf_][0][ebase]);                    \
    GLOAD16(xh + ab_ + 2048 + tid8, &lds[buf_][0][2048 + ebase]);             \
    GLOAD16(wh + bb_ + tid8,        &lds[buf_][1][ebase]);                    \
    GLOAD16(wh + bb_ + 2048 + tid8, &lds[buf_][1][2048 + ebase]);             \
  } while (0)

    STAGE(0, 0);
    int buf = 0;

    for (int step = 0; step < NSTEP; ++step) {
        __syncthreads();   // stage(step) landed; everyone done reading buf^1
        if (step < NSTEP - 1) STAGE(buf ^ 1, step + 1);

        if ((step & 7) == 0) {
#pragma unroll
            for (int m = 0; m < 4; ++m)
#pragma unroll
                for (int n = 0; n < 4; ++n) acc[m][n] = (f32x4){0.f, 0.f, 0.f, 0.f};
        }

        f16x8 bh[4];
#pragma unroll
        for (int n = 0; n < 4; ++n)
            bh[n] = *reinterpret_cast<const f16x8*>(
                &lds[buf][1][kch * 1024 + (wc * 64 + n * 16 + frow) * 8]);
#pragma unroll
        for (int m = 0; m < 4; ++m) {
            const f16x8 ah = *reinterpret_cast<const f16x8*>(
                &lds[buf][0][kch * 1024 + (wr * 64 + m * 16 + frow) * 8]);
#pragma unroll
            for (int n = 0; n < 4; ++n)
                acc[m][n] = __builtin_amdgcn_mfma_f32_16x16x32_f16(ah, bh[n], acc[m][n], 0, 0, 0);
        }

        if ((step & 7) == 7) {
            // coltile epilogue: float-domain branchless best-2 (r15-proven).
            // C/D layout: col=lane&15, row=(lane>>4)*4+reg
            const int ct = step >> 3;
            const int cb = by * 512 + ct * 128 + wc * 64 + frow;
            float wq[4];
#pragma unroll
            for (int n = 0; n < 4; ++n) wq[n] = wsq[cb + n * 16];
#pragma unroll
            for (int i = 0; i < 16; ++i) {
                const int m = i >> 2, r = i & 3;
                const float s0 = fmaf(-2.0f, acc[m][0][r], wq[0]);
                const float s1 = fmaf(-2.0f, acc[m][1][r], wq[1]);
                const float s2 = fmaf(-2.0f, acc[m][2][r], wq[2]);
                const float s3 = fmaf(-2.0f, acc[m][3][r], wq[3]);
                const float lo01 = fminf(s0, s1), hi01 = fmaxf(s0, s1);
                const float lo23 = fminf(s2, s3), hi23 = fmaxf(s2, s3);
                const unsigned c01 = s0 <= s1 ? (unsigned)cb : (unsigned)(cb + 16);
                const unsigned c23 = s2 <= s3 ? (unsigned)(cb + 32) : (unsigned)(cb + 48);
                const float l1 = fminf(lo01, lo23);
                const unsigned cl = lo01 <= lo23 ? c01 : c23;
                const float l2 = fminf(fminf(hi01, hi23), fmaxf(lo01, lo23));
                const bool q = l1 < b1v[i];
                const float disp = q ? b1v[i] : l1;       // displaced score
                b1c[i] = q ? cl : b1c[i];
                b1v[i] = fminf(l1, b1v[i]);
                b2v[i] = fminf(fminf(disp, l2), b2v[i]);
            }
        }
        buf ^= 1;
    }
#undef STAGE

    // dump: merge lane^8 partner (sorted-pair) -> 32-col sets; plain stores
#pragma unroll
    for (int i = 0; i < 16; ++i) {
        const float o1v = __shfl_xor(b1v[i], 8, 64);
        const unsigned o1c = __shfl_xor(b1c[i], 8, 64);
        const float o2v = __shfl_xor(b2v[i], 8, 64);
        const float n1 = fminf(b1v[i], o1v);
        const unsigned n1c = b1v[i] <= o1v ? b1c[i] : o1c;
        const float n2 = fminf(fmaxf(b1v[i], o1v), fminf(b2v[i], o2v));
        if ((lane & 8) == 0) {
            const int rowg = rowbase + wr * 64 + (i >> 2) * 16 + kch * 4 + (i & 3);
            const u64 e = ((u64)fkey(n1) << 32) |
                          ((u64)(fkey(n2) >> 14) << 14) | (u64)(n1c & 0x3FFFu);
            plist[(size_t)rowg * 512 + by * 16 + (frow & 7) * 2 + wc] = e;
        }
    }
}

// ---------------- kernel 3: direct rescore + rare set-scan + decode ----------------
__global__ __launch_bounds__(256) void som_rescore(const float* __restrict__ xb,
                                                   const float* __restrict__ wt,
                                                   const float* __restrict__ wsq,
                                                   const u64* __restrict__ plist,
                                                   int* __restrict__ out) {
    const int row = (blockIdx.x * 256 + threadIdx.x) >> 6;   // one wave per row
    const int lane = threadIdx.x & 63;
    if (row >= B_ROWS) return;
    const float4 xv = *reinterpret_cast<const float4*>(xb + (size_t)row * KF + lane * 4);

    // load 512 packed entries (8 sweeps of 64, coalesced); global hh-min over b1k
    u64 ev[8];
    unsigned g = 0xFFFFFFFFu;
#pragma unroll
    for (int sw = 0; sw < 8; ++sw) {
        ev[sw] = plist[(size_t)row * 512 + sw * 64 + lane];
        const unsigned b1 = (unsigned)(ev[sw] >> 32);
        g = b1 < g ? b1 : g;
    }
#pragma unroll
    for (int mkx = 1; mkx <= 32; mkx <<= 1) {
        const unsigned o = __shfl_xor(g, mkx, 64);
        g = o < g ? o : g;
    }
    const unsigned thr_key = fkey(unkey(g) + MARGIN);
    const unsigned thr_t = thr_key >> 14;

    u64 best = ~0ull;
#pragma unroll
    for (int sw = 0; sw < 8; ++sw) {
        const unsigned b1 = (unsigned)(ev[sw] >> 32);
        const unsigned b2t = (unsigned)(ev[sw] >> 14) & 0x3FFFFu;
        const bool scan = b2t <= thr_t;
        // direct rescore of b1col (pairs: two independent reduction chains)
        unsigned long long mask = __ballot(b1 <= thr_key && !scan);
        while (mask) {
            const int s0 = __ffsll(mask) - 1; mask &= mask - 1;
            const bool two = mask != 0ull;
            int s1 = s0;
            if (two) { s1 = __ffsll(mask) - 1; mask &= mask - 1; }
            const int col0 = (int)(__shfl(ev[sw], s0, 64) & 0x3FFFull);
            const int col1 = (int)(__shfl(ev[sw], s1, 64) & 0x3FFFull);
            const float4 w0 = *reinterpret_cast<const float4*>(wt + (size_t)col0 * KF + lane * 4);
            float d0 = xv.x * w0.x + xv.y * w0.y + xv.z * w0.z + xv.w * w0.w;
            float d1 = 0.0f;
            if (two) {
                const float4 w1 = *reinterpret_cast<const float4*>(wt + (size_t)col1 * KF + lane * 4);
                d1 = xv.x * w1.x + xv.y * w1.y + xv.z * w1.z + xv.w * w1.w;
            }
#pragma unroll
            for (int mkx = 1; mkx <= 32; mkx <<= 1) {
                d0 += __shfl_xor(d0, mkx, 64);
                d1 += __shfl_xor(d1, mkx, 64);
            }
            const u64 q0 = ((u64)fkey(wsq[col0] - 2.0f * d0) << 32) | (unsigned)col0;
            if (q0 < best) best = q0;
            if (two) {
                const u64 q1 = ((u64)fkey(wsq[col1] - 2.0f * d1) << 32) | (unsigned)col1;
                if (q1 < best) best = q1;
            }
        }
        // rare: 2+ in-margin cols in one set -> exact scan, 4 cols at a time
        unsigned long long mask2 = __ballot(scan);
        while (mask2) {
            const int src = __ffsll(mask2) - 1;
            mask2 &= mask2 - 1;
            const int s = sw * 64 + src;
            const int chunk = s >> 4, fr8 = (s & 15) >> 1, wcs = s & 1;
#pragma unroll
            for (int ct = 0; ct < 4; ++ct)
#pragma unroll
                for (int h = 0; h < 2; ++h) {
                    float d[4];
                    int colv[4];
#pragma unroll
                    for (int n = 0; n < 4; ++n) {
                        colv[n] = chunk * 512 + ct * 128 + wcs * 64 + n * 16 + fr8 + h * 8;
                        const float4 wv = *reinterpret_cast<const float4*>(wt + (size_t)colv[n] * KF + lane * 4);
                        d[n] = xv.x * wv.x + xv.y * wv.y + xv.z * wv.z + xv.w * wv.w;
                    }
#pragma unroll
                    for (int mkx = 1; mkx <= 32; mkx <<= 1)
#pragma unroll
                        for (int n = 0; n < 4; ++n) d[n] += __shfl_xor(d[n], mkx, 64);
#pragma unroll
                    for (int n = 0; n < 4; ++n) {
                        const u64 q = ((u64)fkey(wsq[colv[n]] - 2.0f * d[n]) << 32) | (unsigned)colv[n];
                        if (q < best) best = q;
                    }
                }
        }
    }

    if (lane == 0) {
        const int idx = (int)(best & 0xffffffffu);
        out[2 * row] = idx >> 7;      // idx / 128
        out[2 * row + 1] = idx & 127; // idx % 128
    }
}

extern "C" void kernel_launch(void* const* d_in, const int* in_sizes, int n_in,
                              void* d_out, int out_size, void* d_ws, size_t ws_size,
                              hipStream_t stream) {
    const float* xb = (const float*)d_in[0];   // [4096, 256] fp32
    const float* wt = (const float*)d_in[1];   // [16384, 256] fp32
    int* out = (int*)d_out;                    // [4096, 2] int32

    char* ws = (char*)d_ws;
    _Float16* xh  = (_Float16*)(ws);                                   // 2 MB
    _Float16* wh  = (_Float16*)(ws + (size_t)2 * 1024 * 1024);         // 8 MB
    float*    wsq = (float*)(ws + (size_t)10 * 1024 * 1024);           // 64 KB
    u64*    plist = (u64*)(ws + (size_t)11 * 1024 * 1024);             // 16 MB

    som_split<<<(B_ROWS * 32 + M_COLS * 32) / 256, 256, 0, stream>>>(xb, wt, xh, wh, wsq);
    som_main<<<BM * NCHUNK / 4, 256, 0, stream>>>(xh, wh, wsq, plist);
    som_rescore<<<B_ROWS / 4, 256, 0, stream>>>(xb, wt, wsq, plist, out);
}

// Round 18
// 63.310 us; speedup vs baseline: 1.1488x; 1.1488x over previous
//
#include <hip/hip_runtime.h>

// SOM BMU: argmin_m (w_sq[m] - 2*dot(x,w[m])) -> (idx/128, idx%128).
// [Round-15 configuration — measured best: 63.2 us total, absmax 0.]
// hh (f16-hi) MFMA GEMM emits per (row, 32-col thread-set) a packed u64:
//   [b1key:32][b2key>>14:18][b1col:14]  (per-thread best-2, float-domain
//   tracking, fkey only at dump; no atomics).
// Rescore: gmin = min b1key (exact hh-min), thr = gmin+MARGIN.
//   b1key<=thr & b2>thr -> direct exact fp32 wave-dot of b1col (~3/row,
//   processed in pairs with interleaved reduction chains).
//   b2(trunc)<=thr -> scan set's 32 cols, 4 at a time (rare; truncation
//   rounds down -> never misses). Coverage: c!=b1col => key(c)>=b2k.
// Margin: |hh-true| <= ~2^-11*||x||*||w|| ~ 0.3 worst; MARGIN=0.75 covers 2E.
// GEMM shape (r9/r13 measured): 128x128 coltile, 4 waves, BK=64, 64KB dbuf.
// r16 (wsq-fold+med3 epilogue) = null; r17 (BK=32 / 4 blk/CU) = -15% — both
// reverted. Binding constraint is the 2-barrier-per-step structure itself.

#define B_ROWS 4096
#define M_COLS 16384
#define KF 256
#define BM 128
#define NCHUNK 16
#define NSTEP 32          // 8 coltiles * 4 k-steps (BK=64)
#define MARGIN 0.75f

typedef _Float16 f16x8 __attribute__((ext_vector_type(8)));
typedef float f32x4 __attribute__((ext_vector_type(4)));
typedef unsigned long long u64;

#define GLOAD16(gsrc, ldst) \
  __builtin_amdgcn_global_load_lds((const __attribute__((address_space(1))) void*)(gsrc), \
                                   (__attribute__((address_space(3))) void*)(ldst), 16, 0, 0)

// tile-major: tiles of 128 rows; per (tile,ks32): [kch=4][r=128][8] halves = 8KB
__device__ __forceinline__ size_t tm_idx(int tile, int ks, int kch, int r) {
    return ((((size_t)(tile * 8 + ks)) * 4 + kch) * 128 + r) * 8;
}

__device__ __forceinline__ unsigned fkey(float s) {
    const unsigned u = __float_as_uint(s);
    return u ^ ((unsigned)((int)u >> 31) | 0x80000000u);   // monotone total order
}
__device__ __forceinline__ float unkey(unsigned k) {
    return (k & 0x80000000u) ? __uint_as_float(k & 0x7fffffffu) : __uint_as_float(~k);
}

// ---------------- kernel 1: fused split X and W -> tile-major f16 hi (+ w_sq) ----------------
__global__ __launch_bounds__(256) void som_split(const float* __restrict__ xb,
                                                 const float* __restrict__ wt,
                                                 _Float16* __restrict__ xh,
                                                 _Float16* __restrict__ wh,
                                                 float* __restrict__ wsq) {
    const int bid = blockIdx.x;
    const bool isx = bid < (B_ROWS * 32) / 256;
    const int gid = (isx ? bid : bid - (B_ROWS * 32) / 256) * 256 + threadIdx.x;
    const float* src = isx ? xb : wt;
    _Float16* dst = isx ? xh : wh;
    const int row = gid >> 5;
    const int kg = gid & 31;
    const float4 v0 = *reinterpret_cast<const float4*>(src + (size_t)row * KF + kg * 8);
    const float4 v1 = *reinterpret_cast<const float4*>(src + (size_t)row * KF + kg * 8 + 4);
    const float vv[8] = {v0.x, v0.y, v0.z, v0.w, v1.x, v1.y, v1.z, v1.w};
    f16x8 h;
    float s = 0.0f;
#pragma unroll
    for (int j = 0; j < 8; ++j) {
        h[j] = (_Float16)vv[j];
        s += vv[j] * vv[j];
    }
    *reinterpret_cast<f16x8*>(dst + tm_idx(row >> 7, kg >> 2, kg & 3, row & 127)) = h;
    if (!isx) {
#pragma unroll
        for (int off = 16; off > 0; off >>= 1) s += __shfl_down(s, off, 64);
        if (kg == 0) wsq[row] = s;   // lanes 0 and 32 each own a row
    }
}

// ---------------- kernel 2: hh GEMM + per-set best-2 (float-domain) ----------------
__global__ __launch_bounds__(256, 2) void som_main(const _Float16* __restrict__ xh,
                                                   const _Float16* __restrict__ wh,
                                                   const float* __restrict__ wsq,
                                                   u64* __restrict__ plist) {
    __shared__ _Float16 lds[2][2][8192];   // 64 KB dbuf

    const int tid = threadIdx.x;
    const int lane = tid & 63;
    const int frow = lane & 15;
    const int kch = lane >> 4;
    const int wid = tid >> 6;
    const int wr = wid >> 1;      // wave row (0..1): 64 rows
    const int wc = wid & 1;       // wave col (0..1): 64 cols

    // bijective XCD swizzle (512 blocks, 512%8==0)
    const int id = blockIdx.x;
    const int swz = (id & 7) * 64 + (id >> 3);
    const int bx = swz & 31;      // row tile (0..31)
    const int by = swz >> 5;      // col chunk (0..15)
    const int rowbase = bx * BM;

    const int ebase = (tid & 192) * 8;   // wave-uniform LDS base (halves)
    const int tid8 = tid * 8;

    float b1v[16], b2v[16];       // per-slot best-2 scores over this thread's 32 cols
    unsigned b1c[16];
#pragma unroll
    for (int i = 0; i < 16; ++i) { b1v[i] = b2v[i] = 3.4e38f; b1c[i] = 0u; }

    f32x4 acc[4][4];

#define STAGE(buf_, step_) do {                                               \
    const int ct_ = (step_) >> 2, t_ = (step_) & 3;                           \
    const size_t ab_ = (size_t)(bx * 8 + 2 * t_) * 4096;                      \
    const size_t bb_ = (size_t)((by * 8 + ct_) * 8 + 2 * t_) * 4096;          \
    GLOAD16(xh + ab_ + tid8,        &lds[buf_][0][ebase]);                    \
    GLOAD16(xh + ab_ + 2048 + tid8, &lds[buf_][0][2048 + ebase]);             \
    GLOAD16(xh + ab_ + 4096 + tid8, &lds[buf_][0][4096 + ebase]);             \
    GLOAD16(xh + ab_ + 6144 + tid8, &lds[buf_][0][6144 + ebase]);             \
    GLOAD16(wh + bb_ + tid8,        &lds[buf_][1][ebase]);                    \
    GLOAD16(wh + bb_ + 2048 + tid8, &lds[buf_][1][2048 + ebase]);             \
    GLOAD16(wh + bb_ + 4096 + tid8, &lds[buf_][1][4096 + ebase]);             \
    GLOAD16(wh + bb_ + 6144 + tid8, &lds[buf_][1][6144 + ebase]);             \
  } while (0)

    STAGE(0, 0);
    int buf = 0;

    for (int step = 0; step < NSTEP; ++step) {
        __syncthreads();   // stage(step) landed; everyone done reading buf^1
        if (step < NSTEP - 1) STAGE(buf ^ 1, step + 1);

        if ((step & 3) == 0) {
#pragma unroll
            for (int m = 0; m < 4; ++m)
#pragma unroll
                for (int n = 0; n < 4; ++n) acc[m][n] = (f32x4){0.f, 0.f, 0.f, 0.f};
        }

#pragma unroll
        for (int kk = 0; kk < 2; ++kk) {
            f16x8 bh[4];
#pragma unroll
            for (int n = 0; n < 4; ++n)
                bh[n] = *reinterpret_cast<const f16x8*>(
                    &lds[buf][1][kk * 4096 + kch * 1024 + (wc * 64 + n * 16 + frow) * 8]);
#pragma unroll
            for (int m = 0; m < 4; ++m) {
                const f16x8 ah = *reinterpret_cast<const f16x8*>(
                    &lds[buf][0][kk * 4096 + kch * 1024 + (wr * 64 + m * 16 + frow) * 8]);
#pragma unroll
                for (int n = 0; n < 4; ++n)
                    acc[m][n] = __builtin_amdgcn_mfma_f32_16x16x32_f16(ah, bh[n], acc[m][n], 0, 0, 0);
            }
        }

        if ((step & 3) == 3) {
            // coltile epilogue: float-domain branchless best-2 (no fkey here).
            // C/D layout: col=lane&15, row=(lane>>4)*4+reg
            const int ct = step >> 2;
            const int cb = by * 1024 + ct * 128 + wc * 64 + frow;
            float wq[4];
#pragma unroll
            for (int n = 0; n < 4; ++n) wq[n] = wsq[cb + n * 16];
#pragma unroll
            for (int i = 0; i < 16; ++i) {
                const int m = i >> 2, r = i & 3;
                const float s0 = fmaf(-2.0f, acc[m][0][r], wq[0]);
                const float s1 = fmaf(-2.0f, acc[m][1][r], wq[1]);
                const float s2 = fmaf(-2.0f, acc[m][2][r], wq[2]);
                const float s3 = fmaf(-2.0f, acc[m][3][r], wq[3]);
                const float lo01 = fminf(s0, s1), hi01 = fmaxf(s0, s1);
                const float lo23 = fminf(s2, s3), hi23 = fmaxf(s2, s3);
                const unsigned c01 = s0 <= s1 ? (unsigned)cb : (unsigned)(cb + 16);
                const unsigned c23 = s2 <= s3 ? (unsigned)(cb + 32) : (unsigned)(cb + 48);
                const float l1 = fminf(lo01, lo23);
                const unsigned cl = lo01 <= lo23 ? c01 : c23;
                const float l2 = fminf(fminf(hi01, hi23), fmaxf(lo01, lo23));
                const bool q = l1 < b1v[i];
                const float disp = q ? b1v[i] : l1;       // displaced score
                b1c[i] = q ? cl : b1c[i];
                b1v[i] = fminf(l1, b1v[i]);
                b2v[i] = fminf(fminf(disp, l2), b2v[i]);
            }
        }
        buf ^= 1;
    }
#undef STAGE

    // dump: one packed u64 per (row, set): [b1k:32][b2k>>14:18][b1col:14]
#pragma unroll
    for (int i = 0; i < 16; ++i) {
        const int rowg = rowbase + wr * 64 + (i >> 2) * 16 + kch * 4 + (i & 3);
        const u64 e = ((u64)fkey(b1v[i]) << 32) |
                      ((u64)(fkey(b2v[i]) >> 14) << 14) | (u64)(b1c[i] & 0x3FFFu);
        plist[(size_t)rowg * 512 + by * 32 + frow * 2 + wc] = e;
    }
}

// ---------------- kernel 3: direct rescore + rare set-scan + decode ----------------
__global__ __launch_bounds__(256) void som_rescore(const float* __restrict__ xb,
                                                   const float* __restrict__ wt,
                                                   const float* __restrict__ wsq,
                                                   const u64* __restrict__ plist,
                                                   int* __restrict__ out) {
    const int row = (blockIdx.x * 256 + threadIdx.x) >> 6;   // one wave per row
    const int lane = threadIdx.x & 63;
    if (row >= B_ROWS) return;
    const float4 xv = *reinterpret_cast<const float4*>(xb + (size_t)row * KF + lane * 4);

    // load 512 packed entries (8 sweeps of 64, coalesced); global hh-min over b1k
    u64 ev[8];
    unsigned g = 0xFFFFFFFFu;
#pragma unroll
    for (int sw = 0; sw < 8; ++sw) {
        ev[sw] = plist[(size_t)row * 512 + sw * 64 + lane];
        const unsigned b1 = (unsigned)(ev[sw] >> 32);
        g = b1 < g ? b1 : g;
    }
#pragma unroll
    for (int mkx = 1; mkx <= 32; mkx <<= 1) {
        const unsigned o = __shfl_xor(g, mkx, 64);
        g = o < g ? o : g;
    }
    const unsigned thr_key = fkey(unkey(g) + MARGIN);
    const unsigned thr_t = thr_key >> 14;

    u64 best = ~0ull;
#pragma unroll
    for (int sw = 0; sw < 8; ++sw) {
        const unsigned b1 = (unsigned)(ev[sw] >> 32);
        const unsigned b2t = (unsigned)(ev[sw] >> 14) & 0x3FFFFu;
        const bool scan = b2t <= thr_t;
        // direct rescore of b1col (pairs: two independent reduction chains)
        unsigned long long mask = __ballot(b1 <= thr_key && !scan);
        while (mask) {
            const int s0 = __ffsll(mask) - 1; mask &= mask - 1;
            const bool two = mask != 0ull;
            int s1 = s0;
            if (two) { s1 = __ffsll(mask) - 1; mask &= mask - 1; }
            const int col0 = (int)(__shfl(ev[sw], s0, 64) & 0x3FFFull);
            const int col1 = (int)(__shfl(ev[sw], s1, 64) & 0x3FFFull);
            const float4 w0 = *reinterpret_cast<const float4*>(wt + (size_t)col0 * KF + lane * 4);
            float d0 = xv.x * w0.x + xv.y * w0.y + xv.z * w0.z + xv.w * w0.w;
            float d1 = 0.0f;
            if (two) {
                const float4 w1 = *reinterpret_cast<const float4*>(wt + (size_t)col1 * KF + lane * 4);
                d1 = xv.x * w1.x + xv.y * w1.y + xv.z * w1.z + xv.w * w1.w;
            }
#pragma unroll
            for (int mkx = 1; mkx <= 32; mkx <<= 1) {
                d0 += __shfl_xor(d0, mkx, 64);
                d1 += __shfl_xor(d1, mkx, 64);
            }
            const u64 q0 = ((u64)fkey(wsq[col0] - 2.0f * d0) << 32) | (unsigned)col0;
            if (q0 < best) best = q0;
            if (two) {
                const u64 q1 = ((u64)fkey(wsq[col1] - 2.0f * d1) << 32) | (unsigned)col1;
                if (q1 < best) best = q1;
            }
        }
        // rare: 2+ in-margin cols in one set -> exact scan, 4 cols at a time
        unsigned long long mask2 = __ballot(scan);
        while (mask2) {
            const int src = __ffsll(mask2) - 1;
            mask2 &= mask2 - 1;
            const int s = sw * 64 + src;
            const int chunk = s >> 5, frs = (s & 31) >> 1, wcs = s & 1;
#pragma unroll
            for (int ct = 0; ct < 8; ++ct) {
                float d[4];
                int colv[4];
#pragma unroll
                for (int n = 0; n < 4; ++n) {
                    colv[n] = chunk * 1024 + ct * 128 + wcs * 64 + n * 16 + frs;
                    const float4 wv = *reinterpret_cast<const float4*>(wt + (size_t)colv[n] * KF + lane * 4);
                    d[n] = xv.x * wv.x + xv.y * wv.y + xv.z * wv.z + xv.w * wv.w;
                }
#pragma unroll
                for (int mkx = 1; mkx <= 32; mkx <<= 1)
#pragma unroll
                    for (int n = 0; n < 4; ++n) d[n] += __shfl_xor(d[n], mkx, 64);
#pragma unroll
                for (int n = 0; n < 4; ++n) {
                    const u64 q = ((u64)fkey(wsq[colv[n]] - 2.0f * d[n]) << 32) | (unsigned)colv[n];
                    if (q < best) best = q;
                }
            }
        }
    }

    if (lane == 0) {
        const int idx = (int)(best & 0xffffffffu);
        out[2 * row] = idx >> 7;      // idx / 128
        out[2 * row + 1] = idx & 127; // idx % 128
    }
}

extern "C" void kernel_launch(void* const* d_in, const int* in_sizes, int n_in,
                              void* d_out, int out_size, void* d_ws, size_t ws_size,
                              hipStream_t stream) {
    const float* xb = (const float*)d_in[0];   // [4096, 256] fp32
    const float* wt = (const float*)d_in[1];   // [16384, 256] fp32
    int* out = (int*)d_out;                    // [4096, 2] int32

    char* ws = (char*)d_ws;
    _Float16* xh  = (_Float16*)(ws);                                   // 2 MB
    _Float16* wh  = (_Float16*)(ws + (size_t)2 * 1024 * 1024);         // 8 MB
    float*    wsq = (float*)(ws + (size_t)10 * 1024 * 1024);           // 64 KB
    u64*    plist = (u64*)(ws + (size_t)11 * 1024 * 1024);             // 16 MB

    som_split<<<(B_ROWS * 32 + M_COLS * 32) / 256, 256, 0, stream>>>(xb, wt, xh, wh, wsq);
    som_main<<<BM * NCHUNK / 4, 256, 0, stream>>>(xh, wh, wsq, plist);
    som_rescore<<<B_ROWS / 4, 256, 0, stream>>>(xb, wt, wsq, plist, out);
}